// Round 11
// baseline (10306.907 us; speedup 1.0000x reference)
//
#include <hip/hip_runtime.h>
#include <hip/hip_bf16.h>

#define NB 32
#define NT 512
#define NH 1024
#define G3 3072
#define NWG_MAIN 128
#define NWG_TOTAL 256
#define PK_LDS 98304   // w_hh fragment blob only

typedef __attribute__((ext_vector_type(8))) short short8;
typedef __attribute__((ext_vector_type(4))) float f32x4;
typedef __attribute__((ext_vector_type(4))) unsigned short us4;
typedef unsigned long long u64;

static __device__ __forceinline__ unsigned short f2bf(float f) {
    union { float f; unsigned u; } v; v.f = f;
    if ((v.u & 0x7fffffffu) > 0x7f800000u) return (unsigned short)((v.u >> 16) | 0x0040u);
    unsigned u = v.u + 0x7fffu + ((v.u >> 16) & 1u);
    return (unsigned short)(u >> 16);
}

static __device__ __forceinline__ void coh_store8(u64* p, u64 v) {
    __hip_atomic_store(p, v, __ATOMIC_RELAXED, __HIP_MEMORY_SCOPE_AGENT);
}

// issue 16 coherent (L1/L2-bypassing) 16B loads at stride 64B; NO wait.
static __device__ __forceinline__ void coh_issue16(const char* base, short8 o[16]) {
    asm volatile(
        "global_load_dwordx4 %0,  %16, off sc0 sc1\n\t"
        "global_load_dwordx4 %1,  %16, off offset:64 sc0 sc1\n\t"
        "global_load_dwordx4 %2,  %16, off offset:128 sc0 sc1\n\t"
        "global_load_dwordx4 %3,  %16, off offset:192 sc0 sc1\n\t"
        "global_load_dwordx4 %4,  %16, off offset:256 sc0 sc1\n\t"
        "global_load_dwordx4 %5,  %16, off offset:320 sc0 sc1\n\t"
        "global_load_dwordx4 %6,  %16, off offset:384 sc0 sc1\n\t"
        "global_load_dwordx4 %7,  %16, off offset:448 sc0 sc1\n\t"
        "global_load_dwordx4 %8,  %16, off offset:512 sc0 sc1\n\t"
        "global_load_dwordx4 %9,  %16, off offset:576 sc0 sc1\n\t"
        "global_load_dwordx4 %10, %16, off offset:640 sc0 sc1\n\t"
        "global_load_dwordx4 %11, %16, off offset:704 sc0 sc1\n\t"
        "global_load_dwordx4 %12, %16, off offset:768 sc0 sc1\n\t"
        "global_load_dwordx4 %13, %16, off offset:832 sc0 sc1\n\t"
        "global_load_dwordx4 %14, %16, off offset:896 sc0 sc1\n\t"
        "global_load_dwordx4 %15, %16, off offset:960 sc0 sc1"
        : "=&v"(o[0]), "=&v"(o[1]), "=&v"(o[2]), "=&v"(o[3]),
          "=&v"(o[4]), "=&v"(o[5]), "=&v"(o[6]), "=&v"(o[7]),
          "=&v"(o[8]), "=&v"(o[9]), "=&v"(o[10]), "=&v"(o[11]),
          "=&v"(o[12]), "=&v"(o[13]), "=&v"(o[14]), "=&v"(o[15])
        : "v"(base)
        : "memory");
}

// wait + BIND the 16 loaded tuples so consumers cannot hoist above the wait
#define VMWAIT_BIND16(NSTR, o)                                                 \
    asm volatile("s_waitcnt vmcnt(" NSTR ")"                                   \
        : "+v"(o[0]), "+v"(o[1]), "+v"(o[2]), "+v"(o[3]),                      \
          "+v"(o[4]), "+v"(o[5]), "+v"(o[6]), "+v"(o[7]),                      \
          "+v"(o[8]), "+v"(o[9]), "+v"(o[10]), "+v"(o[11]),                    \
          "+v"(o[12]), "+v"(o[13]), "+v"(o[14]), "+v"(o[15]) :: "memory");     \
    __builtin_amdgcn_sched_barrier(0)

#define MFMA_BF16 __builtin_amdgcn_mfma_f32_16x16x32_bf16

// ---------------- f32 -> bf16 conversion (vectorized) ----------------
__global__ __launch_bounds__(256) void cvt_bf16_v4(const float4* __restrict__ src,
                                                   us4* __restrict__ dst, int n4) {
    for (int i = blockIdx.x * 256 + threadIdx.x; i < n4; i += gridDim.x * 256) {
        float4 v = src[i];
        us4 o;
        o.x = f2bf(v.x); o.y = f2bf(v.y); o.z = f2bf(v.z); o.w = f2bf(v.w);
        dst[i] = o;
    }
}

// ---------------- x [B][T][D] f32 -> xt [T][B][D] bf16 ----------------
__global__ __launch_bounds__(256) void txp_x(const float4* __restrict__ x, us4* __restrict__ xt) {
    const int total = NT * NB * 256;   // in float4 units
    for (int i = blockIdx.x * 256 + threadIdx.x; i < total; i += gridDim.x * 256) {
        int b = i / (NT * 256);
        int rem = i - b * (NT * 256);
        int t = rem >> 8;
        int d4 = rem & 255;
        float4 v = x[i];
        us4 o;
        o.x = f2bf(v.x); o.y = f2bf(v.y); o.z = f2bf(v.z); o.w = f2bf(v.w);
        xt[((size_t)t * NB + b) * 256 + d4] = o;
    }
}

// ---------------- init hidden bf16 shadows ----------------
__global__ __launch_bounds__(256) void init_h(const float* __restrict__ hid,
                                              unsigned short* __restrict__ h0b,
                                              unsigned short* __restrict__ h1b) {
    int i = blockIdx.x * 256 + threadIdx.x;   // grid covers exactly NB*NH
    h0b[i] = f2bf(hid[i]);
    h1b[i] = f2bf(hid[NB * NH + i]);
}

// ---------------- persistent 2-layer GRU + MEMORY-clock heaters ----------------
// bid 0..127: GRU (exactly r8). bid 128..255: heater WGs stream HBM via
// sc0 sc1 nt loads (bypass all caches) to force the memory/fabric clocks
// (MCLK/FCLK) out of their low P-state — probe for the 15.6us/step plateau.
__global__ __launch_bounds__(128, 1) void gru_persistent(
    const unsigned short* __restrict__ xt,      // [T][B][1024] bf16
    unsigned short* __restrict__ y0b,           // [T][B][1024] bf16 (coherent)
    const unsigned short* __restrict__ wih0, const unsigned short* __restrict__ whh0,
    const unsigned short* __restrict__ wih1, const unsigned short* __restrict__ whh1,
    const float* __restrict__ bih0, const float* __restrict__ bhh0,
    const float* __restrict__ bih1, const float* __restrict__ bhh1,
    const float* __restrict__ hid,              // [2][B][1024] f32
    unsigned short* __restrict__ hb00, unsigned short* __restrict__ hb01,
    unsigned short* __restrict__ hb10, unsigned short* __restrict__ hb11,
    float* __restrict__ out,                    // y1 [B][T][1024] f32, then h [2][B][1024]
    int* __restrict__ flags,
    const float* __restrict__ xheat)            // 64 MB region heaters stream over
{
    extern __shared__ char lds[];
    short* blob = (short*)lds;   // w_hh A-fragment blob: 48 rows x 1024 K = 96 KB

    const int wg = blockIdx.x;

    if (wg >= NWG_MAIN) {
        // ------------- heater: stream HBM (cache-bypassing) + light VALU -------------
        const int* done_p = flags + 300;                       // once-written done word
        const int tid = threadIdx.x;
        const char* base = (const char*)xheat
                         + (size_t)(wg - NWG_MAIN) * (512 * 1024)   // private 512KB slice
                         + tid * 16;
        unsigned off = 0;
        float acc = 0.f;
        float one = 1.0000001f;
        while (__hip_atomic_load(done_p, __ATOMIC_RELAXED, __HIP_MEMORY_SCOPE_AGENT) == 0) {
            short8 t0, t1, t2, t3, t4, t5, t6, t7;
            const char* p0 = base + (off & (512 * 1024 - 1));
            const char* p1 = base + ((off + 4096) & (512 * 1024 - 1));
            const char* p2 = base + ((off + 8192) & (512 * 1024 - 1));
            const char* p3 = base + ((off + 12288) & (512 * 1024 - 1));
            asm volatile("global_load_dwordx4 %0, %2, off sc0 sc1 nt\n\t"
                         "global_load_dwordx4 %1, %2, off offset:2048 sc0 sc1 nt"
                         : "=&v"(t0), "=&v"(t1) : "v"(p0) : "memory");
            asm volatile("global_load_dwordx4 %0, %2, off sc0 sc1 nt\n\t"
                         "global_load_dwordx4 %1, %2, off offset:2048 sc0 sc1 nt"
                         : "=&v"(t2), "=&v"(t3) : "v"(p1) : "memory");
            asm volatile("global_load_dwordx4 %0, %2, off sc0 sc1 nt\n\t"
                         "global_load_dwordx4 %1, %2, off offset:2048 sc0 sc1 nt"
                         : "=&v"(t4), "=&v"(t5) : "v"(p2) : "memory");
            asm volatile("global_load_dwordx4 %0, %2, off sc0 sc1 nt\n\t"
                         "global_load_dwordx4 %1, %2, off offset:2048 sc0 sc1 nt"
                         : "=&v"(t6), "=&v"(t7) : "v"(p3) : "memory");
            asm volatile("s_waitcnt vmcnt(0)" ::: "memory");
            asm volatile("" :: "v"(t0), "v"(t1), "v"(t2), "v"(t3),
                              "v"(t4), "v"(t5), "v"(t6), "v"(t7));
            off += 16384;
#pragma unroll
            for (int i = 0; i < 64; ++i)
                asm volatile("v_fmac_f32 %0, %1, %1" : "+v"(acc) : "v"(one));
        }
        asm volatile("" :: "v"(acc));
        return;
    }

    const int tid  = threadIdx.x;
    const int lane = tid & 63;
    const int bh   = tid >> 6;        // batch half 0/1
    const int lr   = lane & 15;       // batch-within-half (B) / w-row (A)
    const int lq   = lane >> 4;       // k-octet index

    const int lay   = wg >> 6;
    const int slot  = wg & 63;
    const int j0    = slot * 16;
    const int batch = bh * 16 + lr;
    const int colg  = lq * 4;         // D rows (lane>>4)*4+reg -> cols j0+colg..+3
    const int gc0   = j0 + colg;

    const int* poll_own = flags + lay * 128 + bh * 64 + lane;   // 64 slots, same bh
    const int* poll_y0  = flags + bh * 64 + lane;               // layer-0 flags, same bh
    int* pub = flags + lay * 128 + bh * 64 + slot;

    const unsigned short* wih = lay ? wih1 : wih0;
    const unsigned short* whh = lay ? whh1 : whh0;
    const float* bih = lay ? bih1 : bih0;
    const float* bhh = lay ? bhh1 : bhh0;
    unsigned short* hb[2];
    if (lay == 0) { hb[0] = hb00; hb[1] = hb01; }
    else          { hb[0] = hb10; hb[1] = hb11; }

    // ---- stage w_hh rows {g*1024+j0 .. +16} into LDS A-frag blob ----
    for (int c = tid; c < 6144; c += 128) {
        int g   = c >> 11;
        int rem = c & 2047;
        int kt  = rem >> 6;
        int q   = (rem >> 4) & 3;
        int col = rem & 15;
        *(short8*)(blob + c * 8) =
            *(const short8*)((const short*)whh + (size_t)(g * 1024 + j0 + col) * 1024 + kt * 32 + q * 8);
    }

    // ---- per-lane gate constants + f32 master h in registers ----
    float br_[4], bz_[4], bxn_[4], bhn_[4];
#pragma unroll
    for (int j = 0; j < 4; ++j) {
        int gc = gc0 + j;
        br_[j]  = bih[gc] + bhh[gc];
        bz_[j]  = bih[1024 + gc] + bhh[1024 + gc];
        bxn_[j] = bih[2048 + gc];
        bhn_[j] = bhh[2048 + gc];
    }
    f32x4 hloc = *(const f32x4*)&hid[(size_t)lay * NB * NH + (size_t)batch * 1024 + gc0];

    __syncthreads();   // blob ready (the only block barrier in the kernel)

    const short* wiA = (const short*)wih + (size_t)(j0 + lr) * 1024 + lq * 8;

    for (int t = 0; t < NT; ++t) {
        f32x4 ar  = {0.f,0.f,0.f,0.f};   // r pre-act
        f32x4 az  = {0.f,0.f,0.f,0.f};   // z pre-act
        f32x4 axn = {0.f,0.f,0.f,0.f};   // n proj part
        f32x4 ahn = {0.f,0.f,0.f,0.f};   // n rec part

        // ---------- input projection (before own-h poll: overlaps peers' publish) ----------
        if (lay == 0) {
            const short* Ap = (const short*)xt + ((size_t)t * NB + batch) * 1024 + lq * 8;
#pragma unroll 8
            for (int kt = 0; kt < 32; ++kt) {
                short8 xb = *(const short8*)(Ap + kt * 32);
                short8 w0 = *(const short8*)(wiA + kt * 32);
                short8 w1 = *(const short8*)(wiA + 1048576 + kt * 32);
                short8 w2 = *(const short8*)(wiA + 2097152 + kt * 32);
                ar  = MFMA_BF16(w0, xb, ar, 0, 0, 0);
                az  = MFMA_BF16(w1, xb, az, 0, 0, 0);
                axn = MFMA_BF16(w2, xb, axn, 0, 0, 0);
            }
        } else {
            while (__hip_atomic_load(poll_y0, __ATOMIC_RELAXED, __HIP_MEMORY_SCOPE_AGENT) < t + 1)
                __builtin_amdgcn_s_sleep(2);
            asm volatile("" ::: "memory");
            short8 ya0[16], ya1[16];
            const char* yb = (const char*)y0b + (((size_t)t * NB + batch) * 1024 + lq * 8) * 2;
            coh_issue16(yb, ya0);
            coh_issue16(yb + 1024, ya1);
            VMWAIT_BIND16("16", ya0);
#pragma unroll
            for (int kt = 0; kt < 16; ++kt) {
                short8 w0 = *(const short8*)(wiA + kt * 32);
                short8 w1 = *(const short8*)(wiA + 1048576 + kt * 32);
                short8 w2 = *(const short8*)(wiA + 2097152 + kt * 32);
                ar  = MFMA_BF16(w0, ya0[kt], ar, 0, 0, 0);
                az  = MFMA_BF16(w1, ya0[kt], az, 0, 0, 0);
                axn = MFMA_BF16(w2, ya0[kt], axn, 0, 0, 0);
            }
            VMWAIT_BIND16("0", ya1);
#pragma unroll
            for (int kk = 0; kk < 16; ++kk) {
                const int kt = kk + 16;
                short8 w0 = *(const short8*)(wiA + kt * 32);
                short8 w1 = *(const short8*)(wiA + 1048576 + kt * 32);
                short8 w2 = *(const short8*)(wiA + 2097152 + kt * 32);
                ar  = MFMA_BF16(w0, ya1[kk], ar, 0, 0, 0);
                az  = MFMA_BF16(w1, ya1[kk], az, 0, 0, 0);
                axn = MFMA_BF16(w2, ya1[kk], axn, 0, 0, 0);
            }
        }

        // ---------- recurrent part ----------
        while (__hip_atomic_load(poll_own, __ATOMIC_RELAXED, __HIP_MEMORY_SCOPE_AGENT) < t)
            __builtin_amdgcn_s_sleep(2);
        asm volatile("" ::: "memory");
        {
            short8 ha0[16], ha1[16];
            const char* hbase = (const char*)hb[t & 1] + ((size_t)batch * 1024 + lq * 8) * 2;
            coh_issue16(hbase, ha0);
            coh_issue16(hbase + 1024, ha1);
            VMWAIT_BIND16("16", ha0);
#pragma unroll
            for (int kt = 0; kt < 16; ++kt) {
                short8 b0 = *(const short8*)(blob + kt * 512 + lane * 8);
                short8 b1 = *(const short8*)(blob + (32 + kt) * 512 + lane * 8);
                short8 b2 = *(const short8*)(blob + (64 + kt) * 512 + lane * 8);
                ar  = MFMA_BF16(b0, ha0[kt], ar, 0, 0, 0);
                az  = MFMA_BF16(b1, ha0[kt], az, 0, 0, 0);
                ahn = MFMA_BF16(b2, ha0[kt], ahn, 0, 0, 0);
            }
            VMWAIT_BIND16("0", ha1);
#pragma unroll
            for (int kk = 0; kk < 16; ++kk) {
                const int kt = kk + 16;
                short8 b0 = *(const short8*)(blob + kt * 512 + lane * 8);
                short8 b1 = *(const short8*)(blob + (32 + kt) * 512 + lane * 8);
                short8 b2 = *(const short8*)(blob + (64 + kt) * 512 + lane * 8);
                ar  = MFMA_BF16(b0, ha1[kk], ar, 0, 0, 0);
                az  = MFMA_BF16(b1, ha1[kk], az, 0, 0, 0);
                ahn = MFMA_BF16(b2, ha1[kk], ahn, 0, 0, 0);
            }
        }

        // ---------- gates (all wave-local: batch = lane&15, cols gc0..gc0+3) ----------
        u64 hpack = 0;
        float hv[4];
#pragma unroll
        for (int j = 0; j < 4; ++j) {
            float r  = 1.f / (1.f + __expf(-(ar[j] + br_[j])));
            float z  = 1.f / (1.f + __expf(-(az[j] + bz_[j])));
            float na = axn[j] + bxn_[j] + r * (ahn[j] + bhn_[j]);
            float e2 = __expf(-2.f * na);
            float n  = (1.f - e2) / (1.f + e2);      // tanh(na)
            float h  = (1.f - z) * n + z * hloc[j];
            hloc[j] = h;
            hv[j] = h;
            hpack |= (u64)f2bf(h) << (16 * j);
        }
        coh_store8((u64*)((unsigned short*)hb[(t + 1) & 1] + (size_t)batch * 1024 + gc0), hpack);
        if (lay == 0)
            coh_store8((u64*)(y0b + ((size_t)t * NB + batch) * 1024 + gc0), hpack);

        asm volatile("s_waitcnt vmcnt(0)" ::: "memory");   // drain to LLC
        if (lane == 0)
            __hip_atomic_store(pub, t + 1, __ATOMIC_RELAXED, __HIP_MEMORY_SCOPE_AGENT);

        // non-consumed outputs AFTER publish (off the critical path)
        if (lay == 1) {
            float4 o4; o4.x = hv[0]; o4.y = hv[1]; o4.z = hv[2]; o4.w = hv[3];
            *(float4*)&out[((size_t)batch * NT + t) * 1024 + gc0] = o4;
        }
        if (t == NT - 1) {
            float4 o4; o4.x = hv[0]; o4.y = hv[1]; o4.z = hv[2]; o4.w = hv[3];
            *(float4*)&out[(size_t)NB * NT * 1024 + (size_t)lay * NB * NH + (size_t)batch * 1024 + gc0] = o4;
        }
    }

    // signal heaters to exit (once-written word on an otherwise-idle line)
    if (lay == 1 && slot == 0 && tid == 0)
        __hip_atomic_store(flags + 300, 1, __ATOMIC_RELAXED, __HIP_MEMORY_SCOPE_AGENT);
}

extern "C" void kernel_launch(void* const* d_in, const int* in_sizes, int n_in,
                              void* d_out, int out_size, void* d_ws, size_t ws_size,
                              hipStream_t stream) {
    (void)in_sizes; (void)n_in; (void)out_size; (void)ws_size;

    const float* x     = (const float*)d_in[0];
    const float* hid   = (const float*)d_in[1];
    const float* w_ih0 = (const float*)d_in[2];
    const float* w_hh0 = (const float*)d_in[3];
    const float* b_ih0 = (const float*)d_in[4];
    const float* b_hh0 = (const float*)d_in[5];
    const float* w_ih1 = (const float*)d_in[6];
    const float* w_hh1 = (const float*)d_in[7];
    const float* b_ih1 = (const float*)d_in[8];
    const float* b_hh1 = (const float*)d_in[9];
    float* out = (float*)d_out;

    char* ws = (char*)d_ws;
    size_t off = 0;
    auto alloc = [&](size_t bytes) -> void* {
        void* p = ws + off;
        off += (bytes + 255) & ~(size_t)255;
        return p;
    };

    unsigned short* xtb   = (unsigned short*)alloc((size_t)NT * NB * 1024 * 2);
    unsigned short* y0b   = (unsigned short*)alloc((size_t)NT * NB * 1024 * 2);
    unsigned short* wih0b = (unsigned short*)alloc((size_t)G3 * 1024 * 2);
    unsigned short* whh0b = (unsigned short*)alloc((size_t)G3 * 1024 * 2);
    unsigned short* wih1b = (unsigned short*)alloc((size_t)G3 * 1024 * 2);
    unsigned short* whh1b = (unsigned short*)alloc((size_t)G3 * 1024 * 2);
    unsigned short* hb0[2]; unsigned short* hb1[2];
    for (int i = 0; i < 2; i++) hb0[i] = (unsigned short*)alloc(NB * NH * 2);
    for (int i = 0; i < 2; i++) hb1[i] = (unsigned short*)alloc(NB * NH * 2);
    int* flags = (int*)alloc(2048);   // [layer][bh][64] + done word at +300

    // --- conversions / init ---
    txp_x<<<2048, 256, 0, stream>>>((const float4*)x, (us4*)xtb);
    cvt_bf16_v4<<<512, 256, 0, stream>>>((const float4*)w_ih0, (us4*)wih0b, G3 * 1024 / 4);
    cvt_bf16_v4<<<512, 256, 0, stream>>>((const float4*)w_hh0, (us4*)whh0b, G3 * 1024 / 4);
    cvt_bf16_v4<<<512, 256, 0, stream>>>((const float4*)w_ih1, (us4*)wih1b, G3 * 1024 / 4);
    cvt_bf16_v4<<<512, 256, 0, stream>>>((const float4*)w_hh1, (us4*)whh1b, G3 * 1024 / 4);
    init_h<<<NB * NH / 256, 256, 0, stream>>>(hid, hb0[0], hb1[0]);
    hipMemsetAsync(flags, 0, 2048, stream);

    // --- persistent recurrence (GRU on 128 CUs + HBM-stream heaters on the rest) ---
    (void)hipFuncSetAttribute((const void*)gru_persistent,
                              hipFuncAttributeMaxDynamicSharedMemorySize, PK_LDS);
    gru_persistent<<<NWG_TOTAL, 128, PK_LDS, stream>>>(
        xtb, y0b, wih0b, whh0b, wih1b, whh1b,
        b_ih0, b_hh0, b_ih1, b_hh1, hid,
        hb0[0], hb0[1], hb1[0], hb1[1],
        out, flags, x);
}

// Round 13
// 9916.088 us; speedup vs baseline: 1.0394x; 1.0394x over previous
//
#include <hip/hip_runtime.h>
#include <hip/hip_bf16.h>

#define NB 32
#define NT 512
#define NH 1024
#define G3 3072
#define PK_LDS 98304                 // w_hh 3-gate fragment blob
#define TSLOT 65536                  // bytes per t-slot: [2 bh][32 kt][64 lane][16B]

typedef __attribute__((ext_vector_type(8))) short short8;
typedef __attribute__((ext_vector_type(4))) float f32x4;
typedef __attribute__((ext_vector_type(4))) unsigned short us4;
typedef unsigned long long u64;

static __device__ __forceinline__ unsigned short f2bf_r(float f) {
    union { float f; unsigned u; } v; v.f = f;
    return (unsigned short)((v.u + 0x7fffu + ((v.u >> 16) & 1u)) >> 16);
}

static __device__ __forceinline__ void st8_llc(u64* p, u64 v) {
    asm volatile("global_store_dwordx2 %0, %1, off sc0 sc1" :: "v"(p), "v"(v) : "memory");
}

static __device__ __forceinline__ bool chunk_bad(short8 s) {
    union { short8 s; uint4 u; } c; c.s = s;
    // dword-atomic stores: any still-sentinel dword shows as 0xFFFFFFFF
    return (c.u.x == ~0u) || (c.u.y == ~0u) || (c.u.z == ~0u) || (c.u.w == ~0u);
}

// issue 4 chunk loads (stride 1024B) from one base, no wait
#define LOAD4(arr, i0, bp)                                                     \
    asm volatile(                                                              \
        "global_load_dwordx4 %0, %4, off sc0 sc1\n\t"                          \
        "global_load_dwordx4 %1, %4, off offset:1024 sc0 sc1\n\t"              \
        "global_load_dwordx4 %2, %4, off offset:2048 sc0 sc1\n\t"              \
        "global_load_dwordx4 %3, %4, off offset:3072 sc0 sc1"                  \
        : "=&v"(arr[i0]), "=&v"(arr[i0+1]), "=&v"(arr[i0+2]), "=&v"(arr[i0+3]) \
        : "v"(bp) : "memory")

#define VMWAIT_BIND16(NSTR, o)                                                 \
    asm volatile("s_waitcnt vmcnt(" NSTR ")"                                   \
        : "+v"((o)[0]), "+v"((o)[1]), "+v"((o)[2]), "+v"((o)[3]),              \
          "+v"((o)[4]), "+v"((o)[5]), "+v"((o)[6]), "+v"((o)[7]),              \
          "+v"((o)[8]), "+v"((o)[9]), "+v"((o)[10]), "+v"((o)[11]),            \
          "+v"((o)[12]), "+v"((o)[13]), "+v"((o)[14]), "+v"((o)[15]) :: "memory"); \
    __builtin_amdgcn_sched_barrier(0)

#define RELOAD1(dst, bp)                                                       \
    asm volatile("global_load_dwordx4 %0, %1, off sc0 sc1\n\ts_waitcnt vmcnt(0)" \
        : "=&v"(dst) : "v"(bp) : "memory");                                    \
    __builtin_amdgcn_sched_barrier(0)

// retry-read 32 fragment chunks from a t-slot (coalesced 1KB per instruction)
#define SEQ_READ32(arr, basep)                                                 \
    do {                                                                       \
        _Pragma("unroll")                                                      \
        for (int g_ = 0; g_ < 8; ++g_) { const char* bp_ = (basep) + g_ * 4096; LOAD4(arr, g_ * 4, bp_); } \
        VMWAIT_BIND16("0", arr);                                               \
        VMWAIT_BIND16("0", (arr) + 16);                                        \
        _Pragma("unroll")                                                      \
        for (int i_ = 0; i_ < 32; ++i_) {                                      \
            while (__any(chunk_bad(arr[i_]))) { RELOAD1(arr[i_], (basep) + i_ * 1024); } \
        }                                                                      \
    } while (0)

#define MFMA_BF16 __builtin_amdgcn_mfma_f32_16x16x32_bf16

// ---------------- f32 -> bf16 conversion (vectorized) ----------------
__global__ __launch_bounds__(256) void cvt_bf16_v4(const float4* __restrict__ src,
                                                   us4* __restrict__ dst, int n4) {
    for (int i = blockIdx.x * 256 + threadIdx.x; i < n4; i += gridDim.x * 256) {
        float4 v = src[i];
        us4 o;
        o.x = f2bf_r(v.x); o.y = f2bf_r(v.y); o.z = f2bf_r(v.z); o.w = f2bf_r(v.w);
        dst[i] = o;
    }
}

// ---------------- init hidden into hseq[0] fragment-blob layout ----------------
__global__ __launch_bounds__(256) void init_h_blob(const float* __restrict__ hid,
                                                   unsigned short* __restrict__ hseq0,
                                                   unsigned short* __restrict__ hseq1) {
    int i = blockIdx.x * 256 + threadIdx.x;   // 0..8191 = 2 lay x 32 b x 128 octets
    int lay = i >> 12, rem = i & 4095;
    int b = rem >> 7, co = rem & 127;
    const float* src = hid + (size_t)lay * NB * NH + (size_t)b * 1024 + co * 8;
    unsigned short* base = lay ? hseq1 : hseq0;
    int kt = co >> 2, o = co & 3, bh = b >> 4, lr = b & 15;
    unsigned short* dst = base + bh * 16384 + kt * 512 + (o * 16 + lr) * 8;  // shorts
    us4 v0, v1;
    v0.x = f2bf_r(src[0]); v0.y = f2bf_r(src[1]); v0.z = f2bf_r(src[2]); v0.w = f2bf_r(src[3]);
    v1.x = f2bf_r(src[4]); v1.y = f2bf_r(src[5]); v1.z = f2bf_r(src[6]); v1.w = f2bf_r(src[7]);
    ((us4*)dst)[0] = v0; ((us4*)dst)[1] = v1;
}

// ---------------- persistent 2-layer GRU, flagless sentinel-synced ----------------
// 128 WGs x 128 thr. WG = (layer, 16-col slot). Wave = batch-half.
// h exchange via t-indexed fragment blobs hseq[lay][t] (no reuse, no flags):
// writers store h-packs (sc0 sc1); readers retry chunks containing sentinel
// dwords (0xFFFFFFFF = bf16 NaN pair, never valid |h|<1 data).
__global__ __launch_bounds__(128, 1) void gru_seq(
    const float* __restrict__ x,                 // [B][T][1024] f32
    const unsigned short* __restrict__ wih0, const unsigned short* __restrict__ whh0,
    const unsigned short* __restrict__ wih1, const unsigned short* __restrict__ whh1,
    const float* __restrict__ bih0, const float* __restrict__ bhh0,
    const float* __restrict__ bih1, const float* __restrict__ bhh1,
    const float* __restrict__ hid,
    char* __restrict__ hseq0, char* __restrict__ hseq1,
    float* __restrict__ out)
{
    extern __shared__ char lds[];
    short* blob = (short*)lds;   // w_hh 3-gate fragment blob, 96 KB

    const int tid  = threadIdx.x;
    const int lane = tid & 63;
    const int bh   = tid >> 6;
    const int lr   = lane & 15;
    const int lq   = lane >> 4;

    const int wg    = blockIdx.x;
    const int lay   = wg >> 6;
    const int slot  = wg & 63;
    const int j0    = slot * 16;
    const int batch = bh * 16 + lr;
    const int gc0   = j0 + lq * 4;

    const unsigned short* wih = lay ? wih1 : wih0;
    const unsigned short* whh = lay ? whh1 : whh0;
    const float* bih = lay ? bih1 : bih0;
    const float* bhh = lay ? bhh1 : bhh0;
    char* hseq = lay ? hseq1 : hseq0;

    // ---- stage w_hh (all 3 gates) into LDS fragment blob ----
    for (int c = tid; c < 6144; c += 128) {
        int g = c >> 11, rem = c & 2047;
        int kt = rem >> 6, q = (rem >> 4) & 3, col = rem & 15;
        *(short8*)(blob + c * 8) =
            *(const short8*)((const short*)whh + (size_t)(g * 1024 + j0 + col) * 1024 + kt * 32 + q * 8);
    }

    float br_[4], bz_[4], bxn_[4], bhn_[4];
#pragma unroll
    for (int j = 0; j < 4; ++j) {
        int gc = gc0 + j;
        br_[j]  = bih[gc] + bhh[gc];
        bz_[j]  = bih[1024 + gc] + bhh[1024 + gc];
        bxn_[j] = bih[2048 + gc];
        bhn_[j] = bhh[2048 + gc];
    }
    f32x4 hloc = *(const f32x4*)&hid[(size_t)lay * NB * NH + (size_t)batch * 1024 + gc0];

    __syncthreads();   // blob ready (only block barrier)

    const short* wiA = (const short*)wih + (size_t)(j0 + lr) * 1024 + lq * 8;
    const char* rd_base_off = (const char*)0 + (size_t)bh * 32768 + (size_t)lane * 16;
    // writer destination constants
    const int kt_w = slot >> 1;
    const int o_w  = (slot & 1) * 2 + (lq >> 1);
    const size_t wr_off = (size_t)bh * 32768 + (size_t)kt_w * 1024 + (size_t)(o_w * 16 + lr) * 16 + (size_t)(lq & 1) * 8;

    for (int t = 0; t < NT; ++t) {
        f32x4 ar  = {0.f,0.f,0.f,0.f};
        f32x4 az  = {0.f,0.f,0.f,0.f};
        f32x4 axn = {0.f,0.f,0.f,0.f};
        f32x4 ahn = {0.f,0.f,0.f,0.f};

        // ---------- input projection ----------
        if (lay == 0) {
            const float* xb = x + ((size_t)batch * NT + t) * 1024 + lq * 8;
#pragma unroll 8
            for (int kt = 0; kt < 32; ++kt) {
                float4 a0 = *(const float4*)(xb + kt * 32);
                float4 a1 = *(const float4*)(xb + kt * 32 + 4);
                short8 xf;
                xf[0] = (short)f2bf_r(a0.x); xf[1] = (short)f2bf_r(a0.y);
                xf[2] = (short)f2bf_r(a0.z); xf[3] = (short)f2bf_r(a0.w);
                xf[4] = (short)f2bf_r(a1.x); xf[5] = (short)f2bf_r(a1.y);
                xf[6] = (short)f2bf_r(a1.z); xf[7] = (short)f2bf_r(a1.w);
                short8 w0 = *(const short8*)(wiA + kt * 32);
                short8 w1 = *(const short8*)(wiA + 1048576 + kt * 32);
                short8 w2 = *(const short8*)(wiA + 2097152 + kt * 32);
                ar  = MFMA_BF16(w0, xf, ar, 0, 0, 0);
                az  = MFMA_BF16(w1, xf, az, 0, 0, 0);
                axn = MFMA_BF16(w2, xf, axn, 0, 0, 0);
            }
        } else {
            // y0[t] = h0_{t+1} lives in hseq0[t+1] fragment blob
            short8 pf[32];
            const char* pb = hseq0 + (size_t)(t + 1) * TSLOT + (size_t)(rd_base_off - (const char*)0);
            SEQ_READ32(pf, pb);
#pragma unroll 8
            for (int kt = 0; kt < 32; ++kt) {
                short8 w0 = *(const short8*)(wiA + kt * 32);
                short8 w1 = *(const short8*)(wiA + 1048576 + kt * 32);
                short8 w2 = *(const short8*)(wiA + 2097152 + kt * 32);
                ar  = MFMA_BF16(w0, pf[kt], ar, 0, 0, 0);
                az  = MFMA_BF16(w1, pf[kt], az, 0, 0, 0);
                axn = MFMA_BF16(w2, pf[kt], axn, 0, 0, 0);
            }
        }

        // ---------- recurrent part: h_t from own ring's blob ----------
        {
            short8 hf[32];
            const char* hb = hseq + (size_t)t * TSLOT + (size_t)(rd_base_off - (const char*)0);
            SEQ_READ32(hf, hb);
#pragma unroll 8
            for (int kt = 0; kt < 32; ++kt) {
                short8 c0 = *(const short8*)(blob + kt * 512 + lane * 8);
                short8 c1 = *(const short8*)(blob + (32 + kt) * 512 + lane * 8);
                short8 c2 = *(const short8*)(blob + (64 + kt) * 512 + lane * 8);
                ar  = MFMA_BF16(c0, hf[kt], ar, 0, 0, 0);
                az  = MFMA_BF16(c1, hf[kt], az, 0, 0, 0);
                ahn = MFMA_BF16(c2, hf[kt], ahn, 0, 0, 0);
            }
        }

        // ---------- gates (wave-local) ----------
        u64 hpack = 0;
        float hv[4];
#pragma unroll
        for (int j = 0; j < 4; ++j) {
            float r  = 1.f / (1.f + __expf(-(ar[j] + br_[j])));
            float z  = 1.f / (1.f + __expf(-(az[j] + bz_[j])));
            float na = axn[j] + bxn_[j] + r * (ahn[j] + bhn_[j]);
            float e2 = __expf(-2.f * na);
            float n  = (1.f - e2) / (1.f + e2);
            float h  = (1.f - z) * n + z * hloc[j];
            hloc[j] = h; hv[j] = h;
            hpack |= (u64)f2bf_r(h) << (16 * j);
        }
        // single publish: h_{t+1} into own ring's blob (serves rec AND ring1 proj)
        st8_llc((u64*)(hseq + (size_t)(t + 1) * TSLOT + wr_off), hpack);

        if (lay == 1) {
            float4 o4; o4.x = hv[0]; o4.y = hv[1]; o4.z = hv[2]; o4.w = hv[3];
            *(float4*)&out[((size_t)batch * NT + t) * 1024 + gc0] = o4;
        }
        if (t == NT - 1) {
            float4 o4; o4.x = hv[0]; o4.y = hv[1]; o4.z = hv[2]; o4.w = hv[3];
            *(float4*)&out[(size_t)NB * NT * 1024 + (size_t)lay * NB * NH + (size_t)batch * 1024 + gc0] = o4;
        }
    }
}

extern "C" void kernel_launch(void* const* d_in, const int* in_sizes, int n_in,
                              void* d_out, int out_size, void* d_ws, size_t ws_size,
                              hipStream_t stream) {
    (void)in_sizes; (void)n_in; (void)out_size; (void)ws_size;

    const float* x     = (const float*)d_in[0];
    const float* hid   = (const float*)d_in[1];
    const float* w_ih0 = (const float*)d_in[2];
    const float* w_hh0 = (const float*)d_in[3];
    const float* b_ih0 = (const float*)d_in[4];
    const float* b_hh0 = (const float*)d_in[5];
    const float* w_ih1 = (const float*)d_in[6];
    const float* w_hh1 = (const float*)d_in[7];
    const float* b_ih1 = (const float*)d_in[8];
    const float* b_hh1 = (const float*)d_in[9];
    float* out = (float*)d_out;

    char* ws = (char*)d_ws;
    size_t off = 0;
    auto alloc = [&](size_t bytes) -> void* {
        void* p = ws + off;
        off += (bytes + 255) & ~(size_t)255;
        return p;
    };

    unsigned short* wih0b = (unsigned short*)alloc((size_t)G3 * 1024 * 2);
    unsigned short* whh0b = (unsigned short*)alloc((size_t)G3 * 1024 * 2);
    unsigned short* wih1b = (unsigned short*)alloc((size_t)G3 * 1024 * 2);
    unsigned short* whh1b = (unsigned short*)alloc((size_t)G3 * 1024 * 2);
    char* hseq0 = (char*)alloc((size_t)(NT + 1) * TSLOT);   // 33.6 MB
    char* hseq1 = (char*)alloc((size_t)(NT + 1) * TSLOT);   // 33.6 MB

    // --- sentinel-fill slots 1..NT (slot 0 gets real init below) ---
    hipMemsetAsync(hseq0 + TSLOT, 0xFF, (size_t)NT * TSLOT, stream);
    hipMemsetAsync(hseq1 + TSLOT, 0xFF, (size_t)NT * TSLOT, stream);

    // --- weight conversions + h0 blob init ---
    cvt_bf16_v4<<<512, 256, 0, stream>>>((const float4*)w_ih0, (us4*)wih0b, G3 * 1024 / 4);
    cvt_bf16_v4<<<512, 256, 0, stream>>>((const float4*)w_hh0, (us4*)whh0b, G3 * 1024 / 4);
    cvt_bf16_v4<<<512, 256, 0, stream>>>((const float4*)w_ih1, (us4*)wih1b, G3 * 1024 / 4);
    cvt_bf16_v4<<<512, 256, 0, stream>>>((const float4*)w_hh1, (us4*)whh1b, G3 * 1024 / 4);
    init_h_blob<<<32, 256, 0, stream>>>(hid, (unsigned short*)hseq0, (unsigned short*)hseq1);

    // --- persistent recurrence, flagless ---
    (void)hipFuncSetAttribute((const void*)gru_seq,
                              hipFuncAttributeMaxDynamicSharedMemorySize, PK_LDS);
    gru_seq<<<128, 128, PK_LDS, stream>>>(
        x, wih0b, whh0b, wih1b, whh1b,
        b_ih0, b_hh0, b_ih1, b_hh1, hid,
        hseq0, hseq1, out);
}

// Round 14
// 9800.739 us; speedup vs baseline: 1.0516x; 1.0118x over previous
//
#include <hip/hip_runtime.h>
#include <hip/hip_bf16.h>

#define NB 32
#define NT 512
#define NH 1024
#define G3 3072
#define PK_LDS 98304                 // w_hh 3-gate fragment blob
#define TSLOT 65536                  // bytes per t-slot: [2 bh][32 kt][64 lane][16B]

typedef __attribute__((ext_vector_type(8))) short short8;
typedef __attribute__((ext_vector_type(4))) float f32x4;
typedef __attribute__((ext_vector_type(4))) unsigned short us4;
typedef unsigned long long u64;

static __device__ __forceinline__ unsigned short f2bf_r(float f) {
    union { float f; unsigned u; } v; v.f = f;
    return (unsigned short)((v.u + 0x7fffu + ((v.u >> 16) & 1u)) >> 16);
}

static __device__ __forceinline__ void st8_llc(u64* p, u64 v) {
    asm volatile("global_store_dwordx2 %0, %1, off sc0 sc1" :: "v"(p), "v"(v) : "memory");
}

static __device__ __forceinline__ bool chunk_bad(short8 s) {
    union { short8 s; uint4 u; } c; c.s = s;
    // dword-atomic stores: any still-sentinel dword shows as 0xFFFFFFFF
    return (c.u.x == ~0u) || (c.u.y == ~0u) || (c.u.z == ~0u) || (c.u.w == ~0u);
}

// ---- named-octet load machinery (spill-proof: no arrays, no per-chunk loops) ----
#define DECL8(p) short8 p##0, p##1, p##2, p##3, p##4, p##5, p##6, p##7

#define ISSUE8(p, bp, BITS)                                                    \
    { const char* bp2_ = (const char*)(bp) + 4096;                             \
    asm volatile(                                                              \
        "global_load_dwordx4 %0, %8, off " BITS "\n\t"                         \
        "global_load_dwordx4 %1, %8, off offset:1024 " BITS "\n\t"             \
        "global_load_dwordx4 %2, %8, off offset:2048 " BITS "\n\t"             \
        "global_load_dwordx4 %3, %8, off offset:3072 " BITS "\n\t"             \
        "global_load_dwordx4 %4, %9, off " BITS "\n\t"                         \
        "global_load_dwordx4 %5, %9, off offset:1024 " BITS "\n\t"             \
        "global_load_dwordx4 %6, %9, off offset:2048 " BITS "\n\t"             \
        "global_load_dwordx4 %7, %9, off offset:3072 " BITS                    \
        : "=&v"(p##0), "=&v"(p##1), "=&v"(p##2), "=&v"(p##3),                  \
          "=&v"(p##4), "=&v"(p##5), "=&v"(p##6), "=&v"(p##7)                   \
        : "v"(bp), "v"(bp2_) : "memory"); }

#define WAITBIND8(NSTR, p)                                                     \
    asm volatile("s_waitcnt vmcnt(" NSTR ")"                                   \
        : "+v"(p##0), "+v"(p##1), "+v"(p##2), "+v"(p##3),                      \
          "+v"(p##4), "+v"(p##5), "+v"(p##6), "+v"(p##7) :: "memory");         \
    __builtin_amdgcn_sched_barrier(0)

#define BAD8(p) (chunk_bad(p##0) || chunk_bad(p##1) || chunk_bad(p##2) ||      \
                 chunk_bad(p##3) || chunk_bad(p##4) || chunk_bad(p##5) ||      \
                 chunk_bad(p##6) || chunk_bad(p##7))

// batched uncached retry: one LLC round trip per round, all 8 chunks at once
#define RETRY8(p, bp)                                                          \
    while (__any(BAD8(p))) { ISSUE8(p, bp, "sc0 sc1"); WAITBIND8("0", p); }

#define MFMA_BF16 __builtin_amdgcn_mfma_f32_16x16x32_bf16

#define PROJ1(pp, kt)                                                          \
    { short8 w0_ = *(const short8*)(wiA + (kt) * 32);                          \
      short8 w1_ = *(const short8*)(wiA + 1048576 + (kt) * 32);                \
      short8 w2_ = *(const short8*)(wiA + 2097152 + (kt) * 32);                \
      ar  = MFMA_BF16(w0_, pp, ar, 0, 0, 0);                                   \
      az  = MFMA_BF16(w1_, pp, az, 0, 0, 0);                                   \
      axn = MFMA_BF16(w2_, pp, axn, 0, 0, 0); }
#define PROJ8(p, g) PROJ1(p##0,(g)*8+0) PROJ1(p##1,(g)*8+1) PROJ1(p##2,(g)*8+2) \
    PROJ1(p##3,(g)*8+3) PROJ1(p##4,(g)*8+4) PROJ1(p##5,(g)*8+5)                \
    PROJ1(p##6,(g)*8+6) PROJ1(p##7,(g)*8+7)

#define REC1(pp, kt)                                                           \
    { short8 c0_ = *(const short8*)(blob + (kt) * 512 + lane * 8);             \
      short8 c1_ = *(const short8*)(blob + (32 + (kt)) * 512 + lane * 8);      \
      short8 c2_ = *(const short8*)(blob + (64 + (kt)) * 512 + lane * 8);      \
      ar  = MFMA_BF16(c0_, pp, ar, 0, 0, 0);                                   \
      az  = MFMA_BF16(c1_, pp, az, 0, 0, 0);                                   \
      ahn = MFMA_BF16(c2_, pp, ahn, 0, 0, 0); }
#define REC8(p, g) REC1(p##0,(g)*8+0) REC1(p##1,(g)*8+1) REC1(p##2,(g)*8+2)    \
    REC1(p##3,(g)*8+3) REC1(p##4,(g)*8+4) REC1(p##5,(g)*8+5)                   \
    REC1(p##6,(g)*8+6) REC1(p##7,(g)*8+7)

// 32-chunk cached read + sentinel fallback + fused MFMA, double-buffered 8+8
#define READ_WORK(WORK8, baseptr)                                              \
    {   const char* b_ = (const char*)(baseptr);                               \
        ISSUE8(pa, b_, "");                                                    \
        ISSUE8(pb, b_ + 8192, "");                                             \
        WAITBIND8("8", pa); RETRY8(pa, b_);          WORK8(pa, 0);             \
        ISSUE8(pa, b_ + 16384, "");                                            \
        WAITBIND8("8", pb); RETRY8(pb, b_ + 8192);   WORK8(pb, 1);             \
        ISSUE8(pb, b_ + 24576, "");                                            \
        WAITBIND8("8", pa); RETRY8(pa, b_ + 16384);  WORK8(pa, 2);             \
        WAITBIND8("0", pb); RETRY8(pb, b_ + 24576);  WORK8(pb, 3);             \
    }

// ---------------- f32 -> bf16 conversion (vectorized) ----------------
__global__ __launch_bounds__(256) void cvt_bf16_v4(const float4* __restrict__ src,
                                                   us4* __restrict__ dst, int n4) {
    for (int i = blockIdx.x * 256 + threadIdx.x; i < n4; i += gridDim.x * 256) {
        float4 v = src[i];
        us4 o;
        o.x = f2bf_r(v.x); o.y = f2bf_r(v.y); o.z = f2bf_r(v.z); o.w = f2bf_r(v.w);
        dst[i] = o;
    }
}

// ---------------- init hidden into hseq[0] fragment-blob layout ----------------
__global__ __launch_bounds__(256) void init_h_blob(const float* __restrict__ hid,
                                                   unsigned short* __restrict__ hseq0,
                                                   unsigned short* __restrict__ hseq1) {
    int i = blockIdx.x * 256 + threadIdx.x;   // 0..8191 = 2 lay x 32 b x 128 octets
    int lay = i >> 12, rem = i & 4095;
    int b = rem >> 7, co = rem & 127;
    const float* src = hid + (size_t)lay * NB * NH + (size_t)b * 1024 + co * 8;
    unsigned short* base = lay ? hseq1 : hseq0;
    int kt = co >> 2, o = co & 3, bh = b >> 4, lr = b & 15;
    unsigned short* dst = base + bh * 16384 + kt * 512 + (o * 16 + lr) * 8;  // shorts
    us4 v0, v1;
    v0.x = f2bf_r(src[0]); v0.y = f2bf_r(src[1]); v0.z = f2bf_r(src[2]); v0.w = f2bf_r(src[3]);
    v1.x = f2bf_r(src[4]); v1.y = f2bf_r(src[5]); v1.z = f2bf_r(src[6]); v1.w = f2bf_r(src[7]);
    ((us4*)dst)[0] = v0; ((us4*)dst)[1] = v1;
}

// ---------------- persistent 2-layer GRU, flagless, cached-broadcast ----------------
// 128 WGs x 128 thr. WG = (layer, 16-col slot). Wave = batch-half.
// h exchange via t-indexed fragment blobs hseq[lay][t]: writers st8 sc0 sc1;
// readers CACHED-first (L2 dedups the 64-WG broadcast) with batched uncached
// sentinel-retry fallback (0xFFFFFFFF dword = not yet written).
__global__ __launch_bounds__(128, 1) void gru_seq(
    const float* __restrict__ x,                 // [B][T][1024] f32
    const unsigned short* __restrict__ wih0, const unsigned short* __restrict__ whh0,
    const unsigned short* __restrict__ wih1, const unsigned short* __restrict__ whh1,
    const float* __restrict__ bih0, const float* __restrict__ bhh0,
    const float* __restrict__ bih1, const float* __restrict__ bhh1,
    const float* __restrict__ hid,
    char* __restrict__ hseq0, char* __restrict__ hseq1,
    float* __restrict__ out)
{
    extern __shared__ char lds[];
    short* blob = (short*)lds;   // w_hh 3-gate fragment blob, 96 KB

    const int tid  = threadIdx.x;
    const int lane = tid & 63;
    const int bh   = tid >> 6;
    const int lr   = lane & 15;
    const int lq   = lane >> 4;

    const int wg    = blockIdx.x;
    const int lay   = wg >> 6;
    const int slot  = wg & 63;
    const int j0    = slot * 16;
    const int batch = bh * 16 + lr;
    const int gc0   = j0 + lq * 4;

    const unsigned short* wih = lay ? wih1 : wih0;
    const unsigned short* whh = lay ? whh1 : whh0;
    const float* bih = lay ? bih1 : bih0;
    const float* bhh = lay ? bhh1 : bhh0;
    char* hseq = lay ? hseq1 : hseq0;

    // ---- stage w_hh (all 3 gates) into LDS fragment blob ----
    for (int c = tid; c < 6144; c += 128) {
        int g = c >> 11, rem = c & 2047;
        int kt = rem >> 6, q = (rem >> 4) & 3, col = rem & 15;
        *(short8*)(blob + c * 8) =
            *(const short8*)((const short*)whh + (size_t)(g * 1024 + j0 + col) * 1024 + kt * 32 + q * 8);
    }

    float br_[4], bz_[4], bxn_[4], bhn_[4];
#pragma unroll
    for (int j = 0; j < 4; ++j) {
        int gc = gc0 + j;
        br_[j]  = bih[gc] + bhh[gc];
        bz_[j]  = bih[1024 + gc] + bhh[1024 + gc];
        bxn_[j] = bih[2048 + gc];
        bhn_[j] = bhh[2048 + gc];
    }
    f32x4 hloc = *(const f32x4*)&hid[(size_t)lay * NB * NH + (size_t)batch * 1024 + gc0];

    __syncthreads();   // blob ready (only block barrier)

    const short* wiA = (const short*)wih + (size_t)(j0 + lr) * 1024 + lq * 8;
    const size_t rdoff = (size_t)bh * 32768 + (size_t)lane * 16;
    // writer destination constants
    const int kt_w = slot >> 1;
    const int o_w  = (slot & 1) * 2 + (lq >> 1);
    const size_t wr_off = (size_t)bh * 32768 + (size_t)kt_w * 1024 + (size_t)(o_w * 16 + lr) * 16 + (size_t)(lq & 1) * 8;

    for (int t = 0; t < NT; ++t) {
        f32x4 ar  = {0.f,0.f,0.f,0.f};
        f32x4 az  = {0.f,0.f,0.f,0.f};
        f32x4 axn = {0.f,0.f,0.f,0.f};
        f32x4 ahn = {0.f,0.f,0.f,0.f};
        DECL8(pa); DECL8(pb);

        // ---------- input projection ----------
        if (lay == 0) {
            const float* xb = x + ((size_t)batch * NT + t) * 1024 + lq * 8;
#pragma unroll 8
            for (int kt = 0; kt < 32; ++kt) {
                float4 a0 = *(const float4*)(xb + kt * 32);
                float4 a1 = *(const float4*)(xb + kt * 32 + 4);
                short8 xf;
                xf[0] = (short)f2bf_r(a0.x); xf[1] = (short)f2bf_r(a0.y);
                xf[2] = (short)f2bf_r(a0.z); xf[3] = (short)f2bf_r(a0.w);
                xf[4] = (short)f2bf_r(a1.x); xf[5] = (short)f2bf_r(a1.y);
                xf[6] = (short)f2bf_r(a1.z); xf[7] = (short)f2bf_r(a1.w);
                PROJ1(xf, kt);
            }
        } else {
            // y0[t] = h0_{t+1} lives in hseq0[t+1] fragment blob
            READ_WORK(PROJ8, hseq0 + (size_t)(t + 1) * TSLOT + rdoff);
        }

        // ---------- recurrent part: h_t from own ring's blob ----------
        READ_WORK(REC8, hseq + (size_t)t * TSLOT + rdoff);

        // ---------- gates (wave-local) ----------
        u64 hpack = 0;
        float hv[4];
#pragma unroll
        for (int j = 0; j < 4; ++j) {
            float r  = 1.f / (1.f + __expf(-(ar[j] + br_[j])));
            float z  = 1.f / (1.f + __expf(-(az[j] + bz_[j])));
            float na = axn[j] + bxn_[j] + r * (ahn[j] + bhn_[j]);
            float e2 = __expf(-2.f * na);
            float n  = (1.f - e2) / (1.f + e2);
            float h  = (1.f - z) * n + z * hloc[j];
            hloc[j] = h; hv[j] = h;
            hpack |= (u64)f2bf_r(h) << (16 * j);
        }
        // single publish: h_{t+1} into own ring's blob (serves rec AND ring1 proj)
        st8_llc((u64*)(hseq + (size_t)(t + 1) * TSLOT + wr_off), hpack);

        if (lay == 1) {
            float4 o4; o4.x = hv[0]; o4.y = hv[1]; o4.z = hv[2]; o4.w = hv[3];
            *(float4*)&out[((size_t)batch * NT + t) * 1024 + gc0] = o4;
        }
        if (t == NT - 1) {
            float4 o4; o4.x = hv[0]; o4.y = hv[1]; o4.z = hv[2]; o4.w = hv[3];
            *(float4*)&out[(size_t)NB * NT * 1024 + (size_t)lay * NB * NH + (size_t)batch * 1024 + gc0] = o4;
        }
    }
}

extern "C" void kernel_launch(void* const* d_in, const int* in_sizes, int n_in,
                              void* d_out, int out_size, void* d_ws, size_t ws_size,
                              hipStream_t stream) {
    (void)in_sizes; (void)n_in; (void)out_size; (void)ws_size;

    const float* x     = (const float*)d_in[0];
    const float* hid   = (const float*)d_in[1];
    const float* w_ih0 = (const float*)d_in[2];
    const float* w_hh0 = (const float*)d_in[3];
    const float* b_ih0 = (const float*)d_in[4];
    const float* b_hh0 = (const float*)d_in[5];
    const float* w_ih1 = (const float*)d_in[6];
    const float* w_hh1 = (const float*)d_in[7];
    const float* b_ih1 = (const float*)d_in[8];
    const float* b_hh1 = (const float*)d_in[9];
    float* out = (float*)d_out;

    char* ws = (char*)d_ws;
    size_t off = 0;
    auto alloc = [&](size_t bytes) -> void* {
        void* p = ws + off;
        off += (bytes + 255) & ~(size_t)255;
        return p;
    };

    unsigned short* wih0b = (unsigned short*)alloc((size_t)G3 * 1024 * 2);
    unsigned short* whh0b = (unsigned short*)alloc((size_t)G3 * 1024 * 2);
    unsigned short* wih1b = (unsigned short*)alloc((size_t)G3 * 1024 * 2);
    unsigned short* whh1b = (unsigned short*)alloc((size_t)G3 * 1024 * 2);
    char* hseq0 = (char*)alloc((size_t)(NT + 1) * TSLOT);   // 33.6 MB
    char* hseq1 = (char*)alloc((size_t)(NT + 1) * TSLOT);   // 33.6 MB

    // --- sentinel-fill slots 1..NT (slot 0 gets real init below) ---
    hipMemsetAsync(hseq0 + TSLOT, 0xFF, (size_t)NT * TSLOT, stream);
    hipMemsetAsync(hseq1 + TSLOT, 0xFF, (size_t)NT * TSLOT, stream);

    // --- weight conversions + h0 blob init ---
    cvt_bf16_v4<<<512, 256, 0, stream>>>((const float4*)w_ih0, (us4*)wih0b, G3 * 1024 / 4);
    cvt_bf16_v4<<<512, 256, 0, stream>>>((const float4*)w_hh0, (us4*)whh0b, G3 * 1024 / 4);
    cvt_bf16_v4<<<512, 256, 0, stream>>>((const float4*)w_ih1, (us4*)wih1b, G3 * 1024 / 4);
    cvt_bf16_v4<<<512, 256, 0, stream>>>((const float4*)w_hh1, (us4*)whh1b, G3 * 1024 / 4);
    init_h_blob<<<32, 256, 0, stream>>>(hid, (unsigned short*)hseq0, (unsigned short*)hseq1);

    // --- persistent recurrence, flagless, cached broadcast ---
    (void)hipFuncSetAttribute((const void*)gru_seq,
                              hipFuncAttributeMaxDynamicSharedMemorySize, PK_LDS);
    gru_seq<<<128, 128, PK_LDS, stream>>>(
        x, wih0b, whh0b, wih1b, whh1b,
        b_ih0, b_hh0, b_ih1, b_hh1, hid,
        hseq0, hseq1, out);
}

// Round 15
// 9579.344 us; speedup vs baseline: 1.0760x; 1.0231x over previous
//
#include <hip/hip_runtime.h>
#include <hip/hip_bf16.h>

#define NB 32
#define NT 512
#define NH 1024
#define G3 3072
#define NWG 128
#define PK_LDS 98304   // w_hh fragment blob

typedef __attribute__((ext_vector_type(8))) short short8;
typedef __attribute__((ext_vector_type(4))) float f32x4;
typedef __attribute__((ext_vector_type(4))) unsigned short us4;
typedef unsigned long long u64;

static __device__ __forceinline__ unsigned short f2bf_r(float f) {
    union { float f; unsigned u; } v; v.f = f;
    return (unsigned short)((v.u + 0x7fffu + ((v.u >> 16) & 1u)) >> 16);
}
static __device__ __forceinline__ float bf2f(unsigned short s) {
    union { unsigned u; float f; } v; v.u = ((unsigned)s) << 16; return v.f;
}
static __device__ __forceinline__ short8 cvt8(const float* p) {
    float4 a0 = *(const float4*)p, a1 = *(const float4*)(p + 4);
    short8 v;
    v[0] = (short)f2bf_r(a0.x); v[1] = (short)f2bf_r(a0.y);
    v[2] = (short)f2bf_r(a0.z); v[3] = (short)f2bf_r(a0.w);
    v[4] = (short)f2bf_r(a1.x); v[5] = (short)f2bf_r(a1.y);
    v[6] = (short)f2bf_r(a1.z); v[7] = (short)f2bf_r(a1.w);
    return v;
}

static __device__ __forceinline__ void coh_store8(u64* p, u64 v) {
    __hip_atomic_store(p, v, __ATOMIC_RELAXED, __HIP_MEMORY_SCOPE_AGENT);
}

// issue 16 coherent (L1/L2-bypassing) 16B loads at stride 64B; NO wait.
static __device__ __forceinline__ void coh_issue16(const char* base, short8 o[16]) {
    asm volatile(
        "global_load_dwordx4 %0,  %16, off sc0 sc1\n\t"
        "global_load_dwordx4 %1,  %16, off offset:64 sc0 sc1\n\t"
        "global_load_dwordx4 %2,  %16, off offset:128 sc0 sc1\n\t"
        "global_load_dwordx4 %3,  %16, off offset:192 sc0 sc1\n\t"
        "global_load_dwordx4 %4,  %16, off offset:256 sc0 sc1\n\t"
        "global_load_dwordx4 %5,  %16, off offset:320 sc0 sc1\n\t"
        "global_load_dwordx4 %6,  %16, off offset:384 sc0 sc1\n\t"
        "global_load_dwordx4 %7,  %16, off offset:448 sc0 sc1\n\t"
        "global_load_dwordx4 %8,  %16, off offset:512 sc0 sc1\n\t"
        "global_load_dwordx4 %9,  %16, off offset:576 sc0 sc1\n\t"
        "global_load_dwordx4 %10, %16, off offset:640 sc0 sc1\n\t"
        "global_load_dwordx4 %11, %16, off offset:704 sc0 sc1\n\t"
        "global_load_dwordx4 %12, %16, off offset:768 sc0 sc1\n\t"
        "global_load_dwordx4 %13, %16, off offset:832 sc0 sc1\n\t"
        "global_load_dwordx4 %14, %16, off offset:896 sc0 sc1\n\t"
        "global_load_dwordx4 %15, %16, off offset:960 sc0 sc1"
        : "=&v"(o[0]), "=&v"(o[1]), "=&v"(o[2]), "=&v"(o[3]),
          "=&v"(o[4]), "=&v"(o[5]), "=&v"(o[6]), "=&v"(o[7]),
          "=&v"(o[8]), "=&v"(o[9]), "=&v"(o[10]), "=&v"(o[11]),
          "=&v"(o[12]), "=&v"(o[13]), "=&v"(o[14]), "=&v"(o[15])
        : "v"(base)
        : "memory");
}

#define VMWAIT_BIND16(NSTR, o)                                                 \
    asm volatile("s_waitcnt vmcnt(" NSTR ")"                                   \
        : "+v"(o[0]), "+v"(o[1]), "+v"(o[2]), "+v"(o[3]),                      \
          "+v"(o[4]), "+v"(o[5]), "+v"(o[6]), "+v"(o[7]),                      \
          "+v"(o[8]), "+v"(o[9]), "+v"(o[10]), "+v"(o[11]),                    \
          "+v"(o[12]), "+v"(o[13]), "+v"(o[14]), "+v"(o[15]) :: "memory");     \
    __builtin_amdgcn_sched_barrier(0)

#define MFMA_BF16 __builtin_amdgcn_mfma_f32_16x16x32_bf16

// ---------------- f32 -> bf16 conversion (vectorized) ----------------
__global__ __launch_bounds__(256) void cvt_bf16_v4(const float4* __restrict__ src,
                                                   us4* __restrict__ dst, int n4) {
    for (int i = blockIdx.x * 256 + threadIdx.x; i < n4; i += gridDim.x * 256) {
        float4 v = src[i];
        us4 o;
        o.x = f2bf_r(v.x); o.y = f2bf_r(v.y); o.z = f2bf_r(v.z); o.w = f2bf_r(v.w);
        dst[i] = o;
    }
}

// ---------------- init hidden bf16 shadows ----------------
__global__ __launch_bounds__(256) void init_h(const float* __restrict__ hid,
                                              unsigned short* __restrict__ h0b,
                                              unsigned short* __restrict__ h1b) {
    int i = blockIdx.x * 256 + threadIdx.x;
    h0b[i] = f2bf_r(hid[i]);
    h1b[i] = f2bf_r(hid[NB * NH + i]);
}

// ---------------- bf16-MFMA GEMM with f32 inputs (inline cvt): C = A*W^T + bias ----------------
__global__ __launch_bounds__(256) void gemm_nt_f32(const float* __restrict__ A,
                                                   const float* __restrict__ W,
                                                   const float* __restrict__ bias,
                                                   unsigned short* __restrict__ C, int M, int N) {
    __shared__ short As[128][40];
    __shared__ short Bs[128][40];
    int tid = threadIdx.x;
    int nblk = N >> 7;
    int bn = blockIdx.x % nblk, bm = blockIdx.x / nblk;
    int lane = tid & 63, w = tid >> 6;
    int wm = w >> 1, wn = w & 1;
    int lr = lane & 15, lk = lane >> 4;
    f32x4 acc[4][4];
#pragma unroll
    for (int i = 0; i < 4; i++)
#pragma unroll
        for (int j = 0; j < 4; j++) acc[i][j] = (f32x4){0.f,0.f,0.f,0.f};
    int r0 = tid >> 2, kc = (tid & 3) * 8;
    for (int k0 = 0; k0 < 1024; k0 += 32) {
        __syncthreads();
#pragma unroll
        for (int jj = 0; jj < 2; jj++) {
            int row = r0 + jj * 64;
            *(short8*)&As[row][kc] = cvt8(&A[(size_t)(bm * 128 + row) * 1024 + k0 + kc]);
            *(short8*)&Bs[row][kc] = cvt8(&W[(size_t)(bn * 128 + row) * 1024 + k0 + kc]);
        }
        __syncthreads();
        short8 af[4], bf[4];
#pragma unroll
        for (int mi = 0; mi < 4; mi++) af[mi] = *(const short8*)&As[wm * 64 + mi * 16 + lr][lk * 8];
#pragma unroll
        for (int ni = 0; ni < 4; ni++) bf[ni] = *(const short8*)&Bs[wn * 64 + ni * 16 + lr][lk * 8];
#pragma unroll
        for (int mi = 0; mi < 4; mi++)
#pragma unroll
            for (int ni = 0; ni < 4; ni++)
                acc[mi][ni] = MFMA_BF16(af[mi], bf[ni], acc[mi][ni], 0, 0, 0);
    }
#pragma unroll
    for (int mi = 0; mi < 4; mi++)
#pragma unroll
        for (int ni = 0; ni < 4; ni++) {
            int gr = bm * 128 + wm * 64 + mi * 16 + lk * 4;
            int gc = bn * 128 + wn * 64 + ni * 16 + lr;
            float bv = bias[gc];
#pragma unroll
            for (int r = 0; r < 4; r++)
                C[(size_t)(gr + r) * N + gc] = f2bf_r(acc[mi][ni][r] + bv);
        }
}

// ---------------- persistent 2-layer GRU (r8 fabric, xp0 precomputed, tight-spin polls) ----------------
__global__ __launch_bounds__(128, 1) void gru_persistent(
    const unsigned short* __restrict__ xp0,     // [B*T][3072] bf16 pre-acts (b_ih0 folded)
    unsigned short* __restrict__ y0b,           // [T][B][1024] bf16 (coherent)
    const unsigned short* __restrict__ wih1b,   // bf16
    const float* __restrict__ whh0, const float* __restrict__ whh1,   // f32 (blob-staged)
    const float* __restrict__ bhh0,
    const float* __restrict__ bih1, const float* __restrict__ bhh1,
    const float* __restrict__ hid,              // [2][B][1024] f32
    unsigned short* __restrict__ hb00, unsigned short* __restrict__ hb01,
    unsigned short* __restrict__ hb10, unsigned short* __restrict__ hb11,
    float* __restrict__ out,                    // y1 [B][T][1024] f32, then h [2][B][1024]
    int* __restrict__ flags)
{
    extern __shared__ char lds[];
    short* blob = (short*)lds;   // w_hh A-fragment blob: 48 rows x 1024 K = 96 KB

    const int tid  = threadIdx.x;
    const int lane = tid & 63;
    const int bh   = tid >> 6;        // batch half 0/1
    const int lr   = lane & 15;
    const int lq   = lane >> 4;

    const int wg    = blockIdx.x;
    const int lay   = wg >> 6;
    const int slot  = wg & 63;
    const int j0    = slot * 16;
    const int batch = bh * 16 + lr;
    const int gc0   = j0 + lq * 4;

    const int* poll_own = flags + lay * 128 + bh * 64 + lane;
    const int* poll_y0  = flags + bh * 64 + lane;
    int* pub = flags + lay * 128 + bh * 64 + slot;

    const float* whh = lay ? whh1 : whh0;
    unsigned short* hb[2];
    if (lay == 0) { hb[0] = hb00; hb[1] = hb01; }
    else          { hb[0] = hb10; hb[1] = hb11; }

    // ---- stage w_hh rows {g*1024+j0..+16} into LDS A-frag blob (f32 -> bf16 inline) ----
    for (int c = tid; c < 6144; c += 128) {
        int g = c >> 11, rem = c & 2047;
        int kt = rem >> 6, q = (rem >> 4) & 3, col = rem & 15;
        *(short8*)(blob + c * 8) =
            cvt8(whh + (size_t)(g * 1024 + j0 + col) * 1024 + kt * 32 + q * 8);
    }

    // ---- per-lane gate constants + f32 master h ----
    float br_[4], bz_[4], bxn_[4], bhn_[4];
#pragma unroll
    for (int j = 0; j < 4; ++j) {
        int gc = gc0 + j;
        if (lay == 0) {   // b_ih0 folded into xp0
            br_[j]  = bhh0[gc];
            bz_[j]  = bhh0[1024 + gc];
            bxn_[j] = 0.f;
            bhn_[j] = bhh0[2048 + gc];
        } else {
            br_[j]  = bih1[gc] + bhh1[gc];
            bz_[j]  = bih1[1024 + gc] + bhh1[1024 + gc];
            bxn_[j] = bih1[2048 + gc];
            bhn_[j] = bhh1[2048 + gc];
        }
    }
    f32x4 hloc = *(const f32x4*)&hid[(size_t)lay * NB * NH + (size_t)batch * 1024 + gc0];

    __syncthreads();   // blob ready (only block barrier)

    const short* wiA = (const short*)wih1b + (size_t)(j0 + lr) * 1024 + lq * 8;
    const size_t aoff_b = (((size_t)(bh * 16 + lr)) * 1024 + lq * 8) * 2;

    for (int t = 0; t < NT; ++t) {
        f32x4 ar  = {0.f,0.f,0.f,0.f};
        f32x4 az  = {0.f,0.f,0.f,0.f};
        f32x4 axn = {0.f,0.f,0.f,0.f};
        f32x4 ahn = {0.f,0.f,0.f,0.f};
        u64 xpr = 0, xpz = 0, xpn = 0;

        if (lay == 0) {
            // xp0 prefetch (plain cached loads; each element read exactly once chip-wide)
            const unsigned short* xpp = xp0 + ((size_t)batch * NT + t) * G3 + gc0;
            xpr = *(const u64*)xpp;
            xpz = *(const u64*)(xpp + 1024);
            xpn = *(const u64*)(xpp + 2048);
        } else {
            // proj from y0 (tight-spin poll; ring0 runs ahead so this mostly hits)
            while (__hip_atomic_load(poll_y0, __ATOMIC_RELAXED, __HIP_MEMORY_SCOPE_AGENT) < t + 1) { }
            asm volatile("" ::: "memory");
            short8 ya0[16], ya1[16];
            const char* yb = (const char*)y0b + ((size_t)t * NB) * 2048 + aoff_b;
            coh_issue16(yb, ya0);
            coh_issue16(yb + 1024, ya1);
            VMWAIT_BIND16("16", ya0);
#pragma unroll
            for (int kt = 0; kt < 16; ++kt) {
                short8 w0 = *(const short8*)(wiA + kt * 32);
                short8 w1 = *(const short8*)(wiA + 1048576 + kt * 32);
                short8 w2 = *(const short8*)(wiA + 2097152 + kt * 32);
                ar  = MFMA_BF16(w0, ya0[kt], ar, 0, 0, 0);
                az  = MFMA_BF16(w1, ya0[kt], az, 0, 0, 0);
                axn = MFMA_BF16(w2, ya0[kt], axn, 0, 0, 0);
            }
            VMWAIT_BIND16("0", ya1);
#pragma unroll
            for (int kk = 0; kk < 16; ++kk) {
                const int kt = kk + 16;
                short8 w0 = *(const short8*)(wiA + kt * 32);
                short8 w1 = *(const short8*)(wiA + 1048576 + kt * 32);
                short8 w2 = *(const short8*)(wiA + 2097152 + kt * 32);
                ar  = MFMA_BF16(w0, ya1[kk], ar, 0, 0, 0);
                az  = MFMA_BF16(w1, ya1[kk], az, 0, 0, 0);
                axn = MFMA_BF16(w2, ya1[kk], axn, 0, 0, 0);
            }
        }

        // ---------- recurrent part ----------
        while (__hip_atomic_load(poll_own, __ATOMIC_RELAXED, __HIP_MEMORY_SCOPE_AGENT) < t) { }
        asm volatile("" ::: "memory");
        {
            short8 ha0[16], ha1[16];
            const char* hbase = (const char*)hb[t & 1] + aoff_b;
            coh_issue16(hbase, ha0);
            coh_issue16(hbase + 1024, ha1);
            VMWAIT_BIND16("16", ha0);
#pragma unroll
            for (int kt = 0; kt < 16; ++kt) {
                short8 b0 = *(const short8*)(blob + kt * 512 + lane * 8);
                short8 b1 = *(const short8*)(blob + (32 + kt) * 512 + lane * 8);
                short8 b2 = *(const short8*)(blob + (64 + kt) * 512 + lane * 8);
                ar  = MFMA_BF16(b0, ha0[kt], ar, 0, 0, 0);
                az  = MFMA_BF16(b1, ha0[kt], az, 0, 0, 0);
                ahn = MFMA_BF16(b2, ha0[kt], ahn, 0, 0, 0);
            }
            VMWAIT_BIND16("0", ha1);
#pragma unroll
            for (int kk = 0; kk < 16; ++kk) {
                const int kt = kk + 16;
                short8 b0 = *(const short8*)(blob + kt * 512 + lane * 8);
                short8 b1 = *(const short8*)(blob + (32 + kt) * 512 + lane * 8);
                short8 b2 = *(const short8*)(blob + (64 + kt) * 512 + lane * 8);
                ar  = MFMA_BF16(b0, ha1[kk], ar, 0, 0, 0);
                az  = MFMA_BF16(b1, ha1[kk], az, 0, 0, 0);
                ahn = MFMA_BF16(b2, ha1[kk], ahn, 0, 0, 0);
            }
        }

        // ---------- gates (wave-local) ----------
        u64 hpack = 0;
        float hv[4];
#pragma unroll
        for (int j = 0; j < 4; ++j) {
            float xr, xz, xn;
            if (lay == 0) {
                xr = bf2f((unsigned short)(xpr >> (16 * j)));
                xz = bf2f((unsigned short)(xpz >> (16 * j)));
                xn = bf2f((unsigned short)(xpn >> (16 * j)));
            } else { xr = 0.f; xz = 0.f; xn = axn[j]; }
            float r  = 1.f / (1.f + __expf(-(xr + ar[j] + br_[j])));
            float z  = 1.f / (1.f + __expf(-(xz + az[j] + bz_[j])));
            float na = xn + bxn_[j] + r * (ahn[j] + bhn_[j]);
            float e2 = __expf(-2.f * na);
            float n  = (1.f - e2) / (1.f + e2);
            float h  = (1.f - z) * n + z * hloc[j];
            hloc[j] = h; hv[j] = h;
            hpack |= (u64)f2bf_r(h) << (16 * j);
        }
        coh_store8((u64*)((unsigned short*)hb[(t + 1) & 1] + (size_t)batch * 1024 + gc0), hpack);
        if (lay == 0)
            coh_store8((u64*)(y0b + ((size_t)t * NB + batch) * 1024 + gc0), hpack);

        asm volatile("s_waitcnt vmcnt(0)" ::: "memory");   // drain to LLC
        if (lane == 0)
            __hip_atomic_store(pub, t + 1, __ATOMIC_RELAXED, __HIP_MEMORY_SCOPE_AGENT);

        if (lay == 1) {
            float4 o4; o4.x = hv[0]; o4.y = hv[1]; o4.z = hv[2]; o4.w = hv[3];
            *(float4*)&out[((size_t)batch * NT + t) * 1024 + gc0] = o4;
        }
        if (t == NT - 1) {
            float4 o4; o4.x = hv[0]; o4.y = hv[1]; o4.z = hv[2]; o4.w = hv[3];
            *(float4*)&out[(size_t)NB * NT * 1024 + (size_t)lay * NB * NH + (size_t)batch * 1024 + gc0] = o4;
        }
    }
}

extern "C" void kernel_launch(void* const* d_in, const int* in_sizes, int n_in,
                              void* d_out, int out_size, void* d_ws, size_t ws_size,
                              hipStream_t stream) {
    (void)in_sizes; (void)n_in; (void)out_size; (void)ws_size;

    const float* x     = (const float*)d_in[0];
    const float* hid   = (const float*)d_in[1];
    const float* w_ih0 = (const float*)d_in[2];
    const float* w_hh0 = (const float*)d_in[3];
    const float* b_ih0 = (const float*)d_in[4];
    const float* b_hh0 = (const float*)d_in[5];
    const float* w_ih1 = (const float*)d_in[6];
    const float* w_hh1 = (const float*)d_in[7];
    const float* b_ih1 = (const float*)d_in[8];
    const float* b_hh1 = (const float*)d_in[9];
    float* out = (float*)d_out;

    char* ws = (char*)d_ws;
    size_t off = 0;
    auto alloc = [&](size_t bytes) -> void* {
        void* p = ws + off;
        off += (bytes + 255) & ~(size_t)255;
        return p;
    };

    const size_t M = (size_t)NB * NT;   // 16384
    unsigned short* xp0   = (unsigned short*)alloc(M * G3 * 2);        // 96 MB
    unsigned short* y0b   = (unsigned short*)alloc((size_t)NT * NB * 1024 * 2);  // 32 MB
    unsigned short* wih1b = (unsigned short*)alloc((size_t)G3 * 1024 * 2);       // 6 MB
    unsigned short* hb0[2]; unsigned short* hb1[2];
    for (int i = 0; i < 2; i++) hb0[i] = (unsigned short*)alloc(NB * NH * 2);
    for (int i = 0; i < 2; i++) hb1[i] = (unsigned short*)alloc(NB * NH * 2);
    int* flags = (int*)alloc(2048);

    // --- prep: xp0 GEMM (f32 in, bf16 out), wih1 bf16 copy, h shadows, flags ---
    gemm_nt_f32<<<(int)(M / 128) * (G3 / 128), 256, 0, stream>>>(x, w_ih0, b_ih0, xp0, (int)M, G3);
    cvt_bf16_v4<<<512, 256, 0, stream>>>((const float4*)w_ih1, (us4*)wih1b, G3 * 1024 / 4);
    init_h<<<NB * NH / 256, 256, 0, stream>>>(hid, hb0[0], hb1[0]);
    hipMemsetAsync(flags, 0, 2048, stream);

    // --- persistent recurrence ---
    (void)hipFuncSetAttribute((const void*)gru_persistent,
                              hipFuncAttributeMaxDynamicSharedMemorySize, PK_LDS);
    gru_persistent<<<NWG, 128, PK_LDS, stream>>>(
        xp0, y0b, wih1b, w_hh0, w_hh1,
        b_hh0, b_ih1, b_hh1, hid,
        hb0[0], hb0[1], hb1[0], hb1[1],
        out, flags);
}